// Round 17
// baseline (760.732 us; speedup 1.0000x reference)
//
#include <hip/hip_runtime.h>

namespace {
constexpr int kB = 1024;
constexpr int kT = 512;
constexpr float kScale = 3.0f * 0.15915494309189535f;  // FREQ / (2*pi)
constexpr size_t kOffP = (size_t)2 * kT * kB;          // start of traj_p
constexpr size_t kOffL = kOffP + (size_t)kT * kB;      // start of logpt
// d_ws layout in floats:
constexpr int kWsM   = 0;     // M[64][64]: col<32 = scale*(W3@W1p), col>=32 = scale*(W3@W1v)
constexpr int kWsMb  = 4096;  // mb[64]  : scale*(b3@W1p | b3@W1v)
constexpr int kWsMO  = 4160;  // MO[64][3]: W3@W_obs
constexpr int kWsMOb = 4352;  // mob[3]  : b3@W_obs
}

typedef unsigned int uint2_t __attribute__((ext_vector_type(2)));
typedef float float2v __attribute__((ext_vector_type(2)));

__global__ void setup_kernel(const float* __restrict__ W1,
                             const float* __restrict__ W3,
                             const float* __restrict__ W_obs,
                             const float* __restrict__ b3,
                             float* __restrict__ ws)
{
    const int tid = blockIdx.x * blockDim.x + threadIdx.x;
    const int nth = gridDim.x * blockDim.x;
    for (int idx = tid; idx < 64 * 64; idx += nth) {
        const int h = idx >> 6, col = idx & 63;
        const int c = col & 31, hv = col >> 5;
        float s = 0.f;
        for (int d = 0; d < 64; ++d)
            s = fmaf(W3[h * 64 + d], W1[(hv * 64 + d) * 32 + c], s);
        ws[kWsM + idx] = kScale * s;
    }
    for (int col = tid; col < 64; col += nth) {
        const int c = col & 31, hv = col >> 5;
        float s = 0.f;
        for (int d = 0; d < 64; ++d)
            s = fmaf(b3[d], W1[(hv * 64 + d) * 32 + c], s);
        ws[kWsMb + col] = kScale * s;
    }
    for (int idx = tid; idx < 64 * 3; idx += nth) {
        const int h = idx / 3, e = idx % 3;
        float s = 0.f;
        for (int d = 0; d < 64; ++d)
            s = fmaf(W3[h * 64 + d], W_obs[d * 3 + e], s);
        ws[kWsMO + idx] = s;
    }
    for (int e = tid; e < 3; e += nth) {
        float s = 0.f;
        for (int d = 0; d < 64; ++d)
            s = fmaf(b3[d], W_obs[d * 3 + e], s);
        ws[kWsMOb + e] = s;
    }
}

// v[lane] + v[lane^32], all-VALU. HW-validated (R9: absmax identical to shfl).
__device__ __forceinline__ float xsum(float v) {
    uint2_t r = __builtin_amdgcn_permlane32_swap(
        __float_as_uint(v), __float_as_uint(v), false, false);
    return __uint_as_float(r.x) + __uint_as_float(r.y);
}

// Packed 2xf32 FMA -> v_pk_fma_f32.
__device__ __forceinline__ float2v pk_fma(float2v a, float2v b, float2v c) {
    return __builtin_elementwise_fma(a, b, c);
}

__global__
__attribute__((amdgpu_flat_work_group_size(64, 64), amdgpu_waves_per_eu(1, 1)))
void ode_seq_kernel(
    const float* __restrict__ latent,
    const float* __restrict__ tarr,
    const float* __restrict__ W_l2d,
    const float* __restrict__ b_l2d,
    const float* __restrict__ W1,
    const float* __restrict__ b1,
    const float* __restrict__ W2,
    const float* __restrict__ b2,
    const float* __restrict__ W_obs,
    const float* __restrict__ b_obs,
    const float* __restrict__ ws,
    float* __restrict__ out)
{
    const int row  = blockIdx.x;
    const int lane = threadIdx.x;
    const int c    = lane & 31;
    const int kh   = lane >> 5;

    __shared__ __align__(16) float sbuf[128];
    __shared__ __align__(16) float sh1[64];   // h1 broadcast buffer
    __shared__ __align__(16) float sh2[64];   // h2 broadcast buffer
    __shared__ float dts[kT];

    for (int i = lane; i < kT - 1; i += 64) dts[i] = tarr[i + 1] - tarr[i];

    sbuf[lane]      = latent[row * 128 + lane];
    sbuf[64 + lane] = latent[row * 128 + 64 + lane];
    __syncthreads();

    // ---- resident weights, volatile-loaded (R11: proven resident) ----
    const volatile float* wsv = ws;
    const volatile float* w2v = W2;

    float2v w2p[16];
    #pragma unroll
    for (int j = 0; j < 16; ++j)
        w2p[j] = float2v{kScale * w2v[(2 * j) * 64 + lane],
                         kScale * w2v[(2 * j + 1) * 64 + lane]};
    float2v w3p[32];
    #pragma unroll
    for (int j = 0; j < 32; ++j)
        w3p[j] = float2v{wsv[kWsM + (2 * j) * 64 + lane],
                         wsv[kWsM + (2 * j + 1) * 64 + lane]};

    const float breg = wsv[kWsMb + lane];
    const float2v mo01 = {wsv[kWsMO + lane * 3 + 0], wsv[kWsMO + lane * 3 + 1]};
    const float mo2 = wsv[kWsMO + lane * 3 + 2];
    const float2v mob01 = (lane == 0)
        ? float2v{wsv[kWsMOb + 0], wsv[kWsMOb + 1]} : float2v{0.f, 0.f};
    const float mobp2 = (lane == 0) ? wsv[kWsMOb + 2] : 0.f;
    const float b2s = kScale * b2[lane];
    const float bo0 = b_obs[0], bo1 = b_obs[1], bo2 = b_obs[2];

    // ---- l1c = scale*(latent @ W1l + b1), replicated to both halves ----
    float l1h = 0.f;
    #pragma unroll 8
    for (int j = 0; j < 64; ++j)
        l1h = fmaf(sbuf[kh * 64 + j], W1[(128 + kh * 64 + j) * 32 + c], l1h);
    const float l1c = kScale * (xsum(l1h) + b1[c]);

    // ---- y0 = latent @ W_l2d + b_l2d ----
    float p0v = b_l2d[lane], v0v = b_l2d[64 + lane];
    #pragma unroll 4
    for (int k = 0; k < 128; ++k) {
        const float lv = sbuf[k];
        p0v = fmaf(lv, W_l2d[k * 128 + lane], p0v);
        v0v = fmaf(lv, W_l2d[k * 128 + 64 + lane], v0v);
    }

    // ---- obs partials (per-lane; reduced only at emit) ----
    const float woa = W_obs[lane * 3 + 0], wob = W_obs[lane * 3 + 1], woc = W_obs[lane * 3 + 2];
    float op0 = p0v * woa, op1 = p0v * wob, op2 = p0v * woc;
    float ov0 = v0v * woa, ov1 = v0v * wob, ov2 = v0v * woc;

    // ---- project state: x = scale*(pos0@W1p | vel0@W1v), V1 = scale*vel0@W1p ----
    __syncthreads();
    sbuf[lane]      = p0v;
    sbuf[64 + lane] = v0v;
    __syncthreads();
    float xacc = 0.f, vacc = 0.f;
    #pragma unroll 4
    for (int j = 0; j < 64; ++j) {
        xacc = fmaf(sbuf[kh * 64 + j], W1[(kh * 64 + j) * 32 + c], xacc);
        vacc = fmaf(sbuf[64 + j],      W1[j * 32 + c],             vacc);
    }
    float x  = kScale * xacc;
    float V1 = kScale * vacc;

    const float4* __restrict__ sh1_4 = reinterpret_cast<const float4*>(sh1);
    const float4* __restrict__ sh2_4 = reinterpret_cast<const float4*>(sh2);

    // dyn: all-LDS broadcast (R14->R16 gradient: each k-group moved from
    // readlane to ds_read_b128 saved ~12 cyc; this is the endpoint).
    // ds_write -> issue all reads -> independent VALU (q's, hoisted RK glue)
    // -> MACs in read order. Accumulator grouping k-mod-4 ascending,
    // (x,y)->accA (z,w)->accB -> bit-identical to R14/R15/R16.
    auto dyn = [&](float xs, float2v& q01, float& q2, float& A) {
        const float pre = xsum(xs) + l1c;
        const float h1 = __builtin_amdgcn_cosf(pre);
        sh1[lane] = h1;                              // ds_write (64 slots)
        float4 rv1[8];
        #pragma unroll
        for (int r = 0; r < 8; ++r) rv1[r] = sh1_4[r];       // k = 0..31
        float2v aA = {b2s, 0.f}, aB = {0.f, 0.f};
        #pragma unroll
        for (int r = 0; r < 8; ++r) {                // k = 0..31 via LDS
            const float2v h01 = {rv1[r].x, rv1[r].y};
            const float2v h23 = {rv1[r].z, rv1[r].w};
            aA = pk_fma(h01, w2p[2 * r + 0], aA);
            aB = pk_fma(h23, w2p[2 * r + 1], aB);
        }
        const float h2 = __builtin_amdgcn_cosf((aA.x + aA.y) + (aB.x + aB.y));
        sh2[lane] = h2;                              // ds_write
        float4 rv2[16];
        #pragma unroll
        for (int r = 0; r < 16; ++r) rv2[r] = sh2_4[r];      // k = 0..63
        q01 = pk_fma(float2v{h2, h2}, mo01, mob01);
        q2  = fmaf(h2, mo2, mobp2);
        float2v cA = {breg, 0.f}, cB = {0.f, 0.f};
        #pragma unroll
        for (int r = 0; r < 16; ++r) {               // k = 0..63 via LDS
            const float2v h01 = {rv2[r].x, rv2[r].y};
            const float2v h23 = {rv2[r].z, rv2[r].w};
            cA = pk_fma(h01, w3p[2 * r + 0], cA);
            cB = pk_fma(h23, w3p[2 * r + 1], cB);
        }
        A = (cA.x + cA.y) + (cB.x + cB.y);
    };

    auto emit = [&](int tt) {
        float r0 = op0, r1 = op1, r2 = op2;
        #pragma unroll
        for (int m = 1; m < 64; m <<= 1) {
            r0 += __shfl_xor(r0, m);
            r1 += __shfl_xor(r1, m);
            r2 += __shfl_xor(r2, m);
        }
        if (lane == 0) {
            *reinterpret_cast<float2*>(out + ((size_t)tt * kB + row) * 2) =
                make_float2(r0 + bo0, r1 + bo1);
            const float z = r2 + bo2;
            out[kOffP + (size_t)tt * kB + row] = 1.f / (1.f + __expf(-z));
            out[kOffL + (size_t)tt * kB + row] = 0.f;
        }
    };

    const bool lo = (kh == 0);
    for (int tt = 0; tt < kT - 1; ++tt) {
        // dyn1 first; emit's DS butterfly interleaves with dyn1's stream.
        float A1, u12; float2v u101; dyn(x, u101, u12, A1);
        const float dt = dts[tt];
        emit(tt);
        const float cc = dt * (1.f / 3.f);
        const float u10 = u101.x, u11 = u101.y;

        const float k1  = lo ? V1 : A1;
        const float x2  = fmaf(cc, k1, x);
        const float V1b = fmaf(cc, A1, V1);
        const float w10 = fmaf(cc, u10, ov0);
        const float w11 = fmaf(cc, u11, ov1);
        const float w12 = fmaf(cc, u12, ov2);

        float A2, u22; float2v u201; dyn(x2, u201, u22, A2);
        const float u20 = u201.x, u21 = u201.y;
        const float k2  = lo ? V1b : A2;
        const float x3  = fmaf(dt, fmaf(-1.f / 3.f, k1, k2), x);
        const float V1c = fmaf(dt, fmaf(-1.f / 3.f, A1, A2), V1);
        const float w20 = fmaf(dt, fmaf(-1.f / 3.f, u10, u20), ov0);
        const float w21 = fmaf(dt, fmaf(-1.f / 3.f, u11, u21), ov1);
        const float w22 = fmaf(dt, fmaf(-1.f / 3.f, u12, u22), ov2);

        float A3, u32; float2v u301; dyn(x3, u301, u32, A3);
        const float u30 = u301.x, u31 = u301.y;
        const float k3  = lo ? V1c : A3;
        const float x4  = fmaf(dt, k1 - k2 + k3, x);
        const float V1d = fmaf(dt, A1 - A2 + A3, V1);
        const float w30 = fmaf(dt, u10 - u20 + u30, ov0);
        const float w31 = fmaf(dt, u11 - u21 + u31, ov1);
        const float w32 = fmaf(dt, u12 - u22 + u32, ov2);

        float A4, u42; float2v u401; dyn(x4, u401, u42, A4);
        const float u40 = u401.x, u41 = u401.y;
        const float k4 = lo ? V1d : A4;

        const float s = dt * 0.125f;
        x   = fmaf(s, k1 + 3.f * (k2 + k3) + k4, x);
        V1  = fmaf(s, A1 + 3.f * (A2 + A3) + A4, V1);
        op0 = fmaf(s, ov0 + 3.f * (w10 + w20) + w30, op0);
        op1 = fmaf(s, ov1 + 3.f * (w11 + w21) + w31, op1);
        op2 = fmaf(s, ov2 + 3.f * (w12 + w22) + w32, op2);
        ov0 = fmaf(s, u10 + 3.f * (u20 + u30) + u40, ov0);
        ov1 = fmaf(s, u11 + 3.f * (u21 + u31) + u41, ov1);
        ov2 = fmaf(s, u12 + 3.f * (u22 + u32) + u42, ov2);
    }
    emit(kT - 1);
}

extern "C" void kernel_launch(void* const* d_in, const int* in_sizes, int n_in,
                              void* d_out, int out_size, void* d_ws, size_t ws_size,
                              hipStream_t stream) {
    (void)in_sizes; (void)n_in; (void)ws_size; (void)out_size;
    const float* latent = (const float*)d_in[0];
    const float* tarr   = (const float*)d_in[1];
    const float* W_l2d  = (const float*)d_in[2];
    const float* b_l2d  = (const float*)d_in[3];
    const float* W1     = (const float*)d_in[4];
    const float* b1     = (const float*)d_in[5];
    const float* W2     = (const float*)d_in[6];
    const float* b2     = (const float*)d_in[7];
    const float* W3     = (const float*)d_in[8];
    const float* b3     = (const float*)d_in[9];
    const float* W_obs  = (const float*)d_in[10];
    const float* b_obs  = (const float*)d_in[11];
    float* ws = (float*)d_ws;

    setup_kernel<<<dim3(18), dim3(256), 0, stream>>>(W1, W3, W_obs, b3, ws);
    ode_seq_kernel<<<dim3(kB), dim3(64), 0, stream>>>(
        latent, tarr, W_l2d, b_l2d, W1, b1, W2, b2, W_obs, b_obs, ws,
        (float*)d_out);
}

// Round 18
// 690.742 us; speedup vs baseline: 1.1013x; 1.1013x over previous
//
#include <hip/hip_runtime.h>

namespace {
constexpr int kB = 1024;
constexpr int kT = 512;
constexpr float kScale = 3.0f * 0.15915494309189535f;  // FREQ / (2*pi)
constexpr size_t kOffP = (size_t)2 * kT * kB;          // start of traj_p
constexpr size_t kOffL = kOffP + (size_t)kT * kB;      // start of logpt
// d_ws layout in floats:
constexpr int kWsM   = 0;     // M[64][64]: col<32 = scale*(W3@W1p), col>=32 = scale*(W3@W1v)
constexpr int kWsMb  = 4096;  // mb[64]  : scale*(b3@W1p | b3@W1v)
constexpr int kWsMO  = 4160;  // MO[64][3]: W3@W_obs
constexpr int kWsMOb = 4352;  // mob[3]  : b3@W_obs
}

typedef unsigned int uint2_t __attribute__((ext_vector_type(2)));
typedef float float2v __attribute__((ext_vector_type(2)));

__global__ void setup_kernel(const float* __restrict__ W1,
                             const float* __restrict__ W3,
                             const float* __restrict__ W_obs,
                             const float* __restrict__ b3,
                             float* __restrict__ ws)
{
    const int tid = blockIdx.x * blockDim.x + threadIdx.x;
    const int nth = gridDim.x * blockDim.x;
    for (int idx = tid; idx < 64 * 64; idx += nth) {
        const int h = idx >> 6, col = idx & 63;
        const int c = col & 31, hv = col >> 5;
        float s = 0.f;
        for (int d = 0; d < 64; ++d)
            s = fmaf(W3[h * 64 + d], W1[(hv * 64 + d) * 32 + c], s);
        ws[kWsM + idx] = kScale * s;
    }
    for (int col = tid; col < 64; col += nth) {
        const int c = col & 31, hv = col >> 5;
        float s = 0.f;
        for (int d = 0; d < 64; ++d)
            s = fmaf(b3[d], W1[(hv * 64 + d) * 32 + c], s);
        ws[kWsMb + col] = kScale * s;
    }
    for (int idx = tid; idx < 64 * 3; idx += nth) {
        const int h = idx / 3, e = idx % 3;
        float s = 0.f;
        for (int d = 0; d < 64; ++d)
            s = fmaf(W3[h * 64 + d], W_obs[d * 3 + e], s);
        ws[kWsMO + idx] = s;
    }
    for (int e = tid; e < 3; e += nth) {
        float s = 0.f;
        for (int d = 0; d < 64; ++d)
            s = fmaf(b3[d], W_obs[d * 3 + e], s);
        ws[kWsMOb + e] = s;
    }
}

__device__ __forceinline__ float rl(float v, int l) {
    return __int_as_float(__builtin_amdgcn_readlane(__float_as_int(v), l));
}

// v[lane] + v[lane^32], all-VALU. HW-validated (R9: absmax identical to shfl).
__device__ __forceinline__ float xsum(float v) {
    uint2_t r = __builtin_amdgcn_permlane32_swap(
        __float_as_uint(v), __float_as_uint(v), false, false);
    return __uint_as_float(r.x) + __uint_as_float(r.y);
}

// Packed 2xf32 FMA -> v_pk_fma_f32.
__device__ __forceinline__ float2v pk_fma(float2v a, float2v b, float2v c) {
    return __builtin_elementwise_fma(a, b, c);
}

template <int CTRL>
__device__ __forceinline__ float dpp_add(float x) {
    return x + __int_as_float(__builtin_amdgcn_update_dpp(
        0, __float_as_int(x), CTRL, 0xF, 0xF, false));
}

// Full-wave sum, all-VALU (no DS ops). Valid in lane 63.
// Chain HW-validated in R5-R7 (absmax identical to shfl butterfly).
__device__ __forceinline__ float wave_sum63(float x) {
    x = dpp_add<0xB1>(x);    // quad_perm xor-1
    x = dpp_add<0x4E>(x);    // quad_perm xor-2
    x = dpp_add<0x124>(x);   // row_ror:4
    x = dpp_add<0x128>(x);   // row_ror:8
    x = dpp_add<0x142>(x);   // row_bcast:15
    x = dpp_add<0x143>(x);   // row_bcast:31
    return x;                // lane 63 holds the full sum
}

__global__
__attribute__((amdgpu_flat_work_group_size(64, 64), amdgpu_waves_per_eu(1, 1)))
void ode_seq_kernel(
    const float* __restrict__ latent,
    const float* __restrict__ tarr,
    const float* __restrict__ W_l2d,
    const float* __restrict__ b_l2d,
    const float* __restrict__ W1,
    const float* __restrict__ b1,
    const float* __restrict__ W2,
    const float* __restrict__ b2,
    const float* __restrict__ W_obs,
    const float* __restrict__ b_obs,
    const float* __restrict__ ws,
    float* __restrict__ out)
{
    const int row  = blockIdx.x;
    const int lane = threadIdx.x;
    const int c    = lane & 31;
    const int kh   = lane >> 5;

    __shared__ __align__(16) float sbuf[128];
    __shared__ __align__(16) float sh1[64];   // h1 broadcast buffer
    __shared__ __align__(16) float sh2[64];   // h2 broadcast buffer
    __shared__ float dts[kT];

    for (int i = lane; i < kT - 1; i += 64) dts[i] = tarr[i + 1] - tarr[i];

    sbuf[lane]      = latent[row * 128 + lane];
    sbuf[64 + lane] = latent[row * 128 + 64 + lane];
    __syncthreads();

    // ---- resident weights, volatile-loaded (R11: proven resident) ----
    const volatile float* wsv = ws;
    const volatile float* w2v = W2;

    float2v w2p[16];
    #pragma unroll
    for (int j = 0; j < 16; ++j)
        w2p[j] = float2v{kScale * w2v[(2 * j) * 64 + lane],
                         kScale * w2v[(2 * j + 1) * 64 + lane]};
    float2v w3p[32];
    #pragma unroll
    for (int j = 0; j < 32; ++j)
        w3p[j] = float2v{wsv[kWsM + (2 * j) * 64 + lane],
                         wsv[kWsM + (2 * j + 1) * 64 + lane]};

    const float breg = wsv[kWsMb + lane];
    const float2v mo01 = {wsv[kWsMO + lane * 3 + 0], wsv[kWsMO + lane * 3 + 1]};
    const float mo2 = wsv[kWsMO + lane * 3 + 2];
    const float2v mob01 = (lane == 0)
        ? float2v{wsv[kWsMOb + 0], wsv[kWsMOb + 1]} : float2v{0.f, 0.f};
    const float mobp2 = (lane == 0) ? wsv[kWsMOb + 2] : 0.f;
    const float b2s = kScale * b2[lane];
    const float bo0 = b_obs[0], bo1 = b_obs[1], bo2 = b_obs[2];

    // ---- l1c = scale*(latent @ W1l + b1), replicated to both halves ----
    float l1h = 0.f;
    #pragma unroll 8
    for (int j = 0; j < 64; ++j)
        l1h = fmaf(sbuf[kh * 64 + j], W1[(128 + kh * 64 + j) * 32 + c], l1h);
    const float l1c = kScale * (xsum(l1h) + b1[c]);

    // ---- y0 = latent @ W_l2d + b_l2d ----
    float p0v = b_l2d[lane], v0v = b_l2d[64 + lane];
    #pragma unroll 4
    for (int k = 0; k < 128; ++k) {
        const float lv = sbuf[k];
        p0v = fmaf(lv, W_l2d[k * 128 + lane], p0v);
        v0v = fmaf(lv, W_l2d[k * 128 + 64 + lane], v0v);
    }

    // ---- obs partials (per-lane; reduced only at emit) ----
    const float woa = W_obs[lane * 3 + 0], wob = W_obs[lane * 3 + 1], woc = W_obs[lane * 3 + 2];
    float op0 = p0v * woa, op1 = p0v * wob, op2 = p0v * woc;
    float ov0 = v0v * woa, ov1 = v0v * wob, ov2 = v0v * woc;

    // ---- project state: x = scale*(pos0@W1p | vel0@W1v), V1 = scale*vel0@W1p ----
    __syncthreads();
    sbuf[lane]      = p0v;
    sbuf[64 + lane] = v0v;
    __syncthreads();
    float xacc = 0.f, vacc = 0.f;
    #pragma unroll 4
    for (int j = 0; j < 64; ++j) {
        xacc = fmaf(sbuf[kh * 64 + j], W1[(kh * 64 + j) * 32 + c], xacc);
        vacc = fmaf(sbuf[64 + j],      W1[j * 32 + c],             vacc);
    }
    float x  = kScale * xacc;
    float V1 = kScale * vacc;

    const float4* __restrict__ sh1_4 = reinterpret_cast<const float4*>(sh1);
    const float4* __restrict__ sh2_4 = reinterpret_cast<const float4*>(sh2);

    // dyn: hybrid broadcast at R16's measured-optimal split.
    // GEMM2: 1 rl j-iter + 7 LDS b128; GEMM3: 2 rl j-iters + 14 LDS b128.
    // Accumulator grouping k-mod-4 ascending, (x,y)->accA (z,w)->accB ->
    // bit-identical to R14/R15/R16.
    auto dyn = [&](float xs, float2v& q01, float& q2, float& A) {
        const float pre = xsum(xs) + l1c;
        const float h1 = __builtin_amdgcn_cosf(pre);
        sh1[lane] = h1;                              // ds_write (64 slots)
        float4 rv1[7];
        #pragma unroll
        for (int r = 0; r < 7; ++r) rv1[r] = sh1_4[1 + r];   // k = 4..31
        float2v aA = {b2s, 0.f}, aB = {0.f, 0.f};
        {                                            // k = 0..3 via readlane
            const float2v h01 = {rl(h1, 0), rl(h1, 1)};
            const float2v h23 = {rl(h1, 2), rl(h1, 3)};
            aA = pk_fma(h01, w2p[0], aA);
            aB = pk_fma(h23, w2p[1], aB);
        }
        #pragma unroll
        for (int r = 0; r < 7; ++r) {                // k = 4..31 via LDS
            const float2v h01 = {rv1[r].x, rv1[r].y};
            const float2v h23 = {rv1[r].z, rv1[r].w};
            aA = pk_fma(h01, w2p[2 + 2 * r + 0], aA);
            aB = pk_fma(h23, w2p[2 + 2 * r + 1], aB);
        }
        const float h2 = __builtin_amdgcn_cosf((aA.x + aA.y) + (aB.x + aB.y));
        sh2[lane] = h2;                              // ds_write
        float4 rv2[14];
        #pragma unroll
        for (int r = 0; r < 14; ++r) rv2[r] = sh2_4[2 + r];  // k = 8..63
        q01 = pk_fma(float2v{h2, h2}, mo01, mob01);
        q2  = fmaf(h2, mo2, mobp2);
        float2v cA = {breg, 0.f}, cB = {0.f, 0.f};
        #pragma unroll
        for (int j = 0; j < 2; ++j) {                // k = 0..7 via readlane
            const float2v h01 = {rl(h2, 4 * j + 0), rl(h2, 4 * j + 1)};
            const float2v h23 = {rl(h2, 4 * j + 2), rl(h2, 4 * j + 3)};
            cA = pk_fma(h01, w3p[2 * j + 0], cA);
            cB = pk_fma(h23, w3p[2 * j + 1], cB);
        }
        #pragma unroll
        for (int r = 0; r < 14; ++r) {               // k = 8..63 via LDS
            const float2v h01 = {rv2[r].x, rv2[r].y};
            const float2v h23 = {rv2[r].z, rv2[r].w};
            cA = pk_fma(h01, w3p[4 + 2 * r + 0], cA);
            cB = pk_fma(h23, w3p[4 + 2 * r + 1], cB);
        }
        A = (cA.x + cA.y) + (cB.x + cB.y);
    };

    // emit: all-VALU DPP tree (no DS ops) -> the DS pipe and lgkmcnt FIFO
    // stay exclusive to dyn's MAC-feed reads. Full sums land in lane 63;
    // store directly from lane 63 (no broadcast needed).
    auto emit = [&](int tt) {
        const float r0 = wave_sum63(op0);
        const float r1 = wave_sum63(op1);
        const float r2 = wave_sum63(op2);
        if (lane == 63) {
            *reinterpret_cast<float2*>(out + ((size_t)tt * kB + row) * 2) =
                make_float2(r0 + bo0, r1 + bo1);
            const float z = r2 + bo2;
            out[kOffP + (size_t)tt * kB + row] = 1.f / (1.f + __expf(-z));
            out[kOffL + (size_t)tt * kB + row] = 0.f;
        }
    };

    const bool lo = (kh == 0);
    for (int tt = 0; tt < kT - 1; ++tt) {
        // dyn1 first; emit's VALU tree interleaves with dyn1's DS waits.
        float A1, u12; float2v u101; dyn(x, u101, u12, A1);
        const float dt = dts[tt];
        emit(tt);
        const float cc = dt * (1.f / 3.f);
        const float u10 = u101.x, u11 = u101.y;

        const float k1  = lo ? V1 : A1;
        const float x2  = fmaf(cc, k1, x);
        const float V1b = fmaf(cc, A1, V1);
        const float w10 = fmaf(cc, u10, ov0);
        const float w11 = fmaf(cc, u11, ov1);
        const float w12 = fmaf(cc, u12, ov2);

        float A2, u22; float2v u201; dyn(x2, u201, u22, A2);
        const float u20 = u201.x, u21 = u201.y;
        const float k2  = lo ? V1b : A2;
        const float x3  = fmaf(dt, fmaf(-1.f / 3.f, k1, k2), x);
        const float V1c = fmaf(dt, fmaf(-1.f / 3.f, A1, A2), V1);
        const float w20 = fmaf(dt, fmaf(-1.f / 3.f, u10, u20), ov0);
        const float w21 = fmaf(dt, fmaf(-1.f / 3.f, u11, u21), ov1);
        const float w22 = fmaf(dt, fmaf(-1.f / 3.f, u12, u22), ov2);

        float A3, u32; float2v u301; dyn(x3, u301, u32, A3);
        const float u30 = u301.x, u31 = u301.y;
        const float k3  = lo ? V1c : A3;
        const float x4  = fmaf(dt, k1 - k2 + k3, x);
        const float V1d = fmaf(dt, A1 - A2 + A3, V1);
        const float w30 = fmaf(dt, u10 - u20 + u30, ov0);
        const float w31 = fmaf(dt, u11 - u21 + u31, ov1);
        const float w32 = fmaf(dt, u12 - u22 + u32, ov2);

        float A4, u42; float2v u401; dyn(x4, u401, u42, A4);
        const float u40 = u401.x, u41 = u401.y;
        const float k4 = lo ? V1d : A4;

        const float s = dt * 0.125f;
        x   = fmaf(s, k1 + 3.f * (k2 + k3) + k4, x);
        V1  = fmaf(s, A1 + 3.f * (A2 + A3) + A4, V1);
        op0 = fmaf(s, ov0 + 3.f * (w10 + w20) + w30, op0);
        op1 = fmaf(s, ov1 + 3.f * (w11 + w21) + w31, op1);
        op2 = fmaf(s, ov2 + 3.f * (w12 + w22) + w32, op2);
        ov0 = fmaf(s, u10 + 3.f * (u20 + u30) + u40, ov0);
        ov1 = fmaf(s, u11 + 3.f * (u21 + u31) + u41, ov1);
        ov2 = fmaf(s, u12 + 3.f * (u22 + u32) + u42, ov2);
    }
    emit(kT - 1);
}

extern "C" void kernel_launch(void* const* d_in, const int* in_sizes, int n_in,
                              void* d_out, int out_size, void* d_ws, size_t ws_size,
                              hipStream_t stream) {
    (void)in_sizes; (void)n_in; (void)ws_size; (void)out_size;
    const float* latent = (const float*)d_in[0];
    const float* tarr   = (const float*)d_in[1];
    const float* W_l2d  = (const float*)d_in[2];
    const float* b_l2d  = (const float*)d_in[3];
    const float* W1     = (const float*)d_in[4];
    const float* b1     = (const float*)d_in[5];
    const float* W2     = (const float*)d_in[6];
    const float* b2     = (const float*)d_in[7];
    const float* W3     = (const float*)d_in[8];
    const float* b3     = (const float*)d_in[9];
    const float* W_obs  = (const float*)d_in[10];
    const float* b_obs  = (const float*)d_in[11];
    float* ws = (float*)d_ws;

    setup_kernel<<<dim3(18), dim3(256), 0, stream>>>(W1, W3, W_obs, b3, ws);
    ode_seq_kernel<<<dim3(kB), dim3(64), 0, stream>>>(
        latent, tarr, W_l2d, b_l2d, W1, b1, W2, b2, W_obs, b_obs, ws,
        (float*)d_out);
}

// Round 19
// 666.220 us; speedup vs baseline: 1.1419x; 1.0368x over previous
//
#include <hip/hip_runtime.h>

namespace {
constexpr int kB = 1024;
constexpr int kT = 512;
constexpr float kScale = 3.0f * 0.15915494309189535f;  // FREQ / (2*pi)
constexpr size_t kOffP = (size_t)2 * kT * kB;          // start of traj_p
constexpr size_t kOffL = kOffP + (size_t)kT * kB;      // start of logpt
// d_ws layout in floats:
constexpr int kWsM   = 0;     // M[64][64]: col<32 = scale*(W3@W1p), col>=32 = scale*(W3@W1v)
constexpr int kWsMb  = 4096;  // mb[64]  : scale*(b3@W1p | b3@W1v)
constexpr int kWsMO  = 4160;  // MO[64][3]: W3@W_obs
constexpr int kWsMOb = 4352;  // mob[3]  : b3@W_obs
}

typedef unsigned int uint2_t __attribute__((ext_vector_type(2)));
typedef float float2v __attribute__((ext_vector_type(2)));

__global__ void setup_kernel(const float* __restrict__ W1,
                             const float* __restrict__ W3,
                             const float* __restrict__ W_obs,
                             const float* __restrict__ b3,
                             float* __restrict__ ws)
{
    const int tid = blockIdx.x * blockDim.x + threadIdx.x;
    const int nth = gridDim.x * blockDim.x;
    for (int idx = tid; idx < 64 * 64; idx += nth) {
        const int h = idx >> 6, col = idx & 63;
        const int c = col & 31, hv = col >> 5;
        float s = 0.f;
        for (int d = 0; d < 64; ++d)
            s = fmaf(W3[h * 64 + d], W1[(hv * 64 + d) * 32 + c], s);
        ws[kWsM + idx] = kScale * s;
    }
    for (int col = tid; col < 64; col += nth) {
        const int c = col & 31, hv = col >> 5;
        float s = 0.f;
        for (int d = 0; d < 64; ++d)
            s = fmaf(b3[d], W1[(hv * 64 + d) * 32 + c], s);
        ws[kWsMb + col] = kScale * s;
    }
    for (int idx = tid; idx < 64 * 3; idx += nth) {
        const int h = idx / 3, e = idx % 3;
        float s = 0.f;
        for (int d = 0; d < 64; ++d)
            s = fmaf(W3[h * 64 + d], W_obs[d * 3 + e], s);
        ws[kWsMO + idx] = s;
    }
    for (int e = tid; e < 3; e += nth) {
        float s = 0.f;
        for (int d = 0; d < 64; ++d)
            s = fmaf(b3[d], W_obs[d * 3 + e], s);
        ws[kWsMOb + e] = s;
    }
}

// v[lane] + v[lane^32], all-VALU. HW-validated (R9: absmax identical to shfl).
__device__ __forceinline__ float xsum(float v) {
    uint2_t r = __builtin_amdgcn_permlane32_swap(
        __float_as_uint(v), __float_as_uint(v), false, false);
    return __uint_as_float(r.x) + __uint_as_float(r.y);
}

// Packed 2xf32 FMA -> v_pk_fma_f32.
__device__ __forceinline__ float2v pk_fma(float2v a, float2v b, float2v c) {
    return __builtin_elementwise_fma(a, b, c);
}

template <int CTRL>
__device__ __forceinline__ float dpp_add(float x) {
    return x + __int_as_float(__builtin_amdgcn_update_dpp(
        0, __float_as_int(x), CTRL, 0xF, 0xF, false));
}

// Full-wave sum, all-VALU (no DS ops). Valid in lane 63.
// Chain HW-validated R5-R7 + R18 (absmax identical).
__device__ __forceinline__ float wave_sum63(float x) {
    x = dpp_add<0xB1>(x);    // quad_perm xor-1
    x = dpp_add<0x4E>(x);    // quad_perm xor-2
    x = dpp_add<0x124>(x);   // row_ror:4
    x = dpp_add<0x128>(x);   // row_ror:8
    x = dpp_add<0x142>(x);   // row_bcast:15
    x = dpp_add<0x143>(x);   // row_bcast:31
    return x;                // lane 63 holds the full sum
}

__global__
__attribute__((amdgpu_flat_work_group_size(64, 64), amdgpu_waves_per_eu(1, 1)))
void ode_seq_kernel(
    const float* __restrict__ latent,
    const float* __restrict__ tarr,
    const float* __restrict__ W_l2d,
    const float* __restrict__ b_l2d,
    const float* __restrict__ W1,
    const float* __restrict__ b1,
    const float* __restrict__ W2,
    const float* __restrict__ b2,
    const float* __restrict__ W_obs,
    const float* __restrict__ b_obs,
    const float* __restrict__ ws,
    float* __restrict__ out)
{
    const int row  = blockIdx.x;
    const int lane = threadIdx.x;
    const int c    = lane & 31;
    const int kh   = lane >> 5;

    __shared__ __align__(16) float sbuf[128];
    __shared__ __align__(16) float sh1[64];   // h1 broadcast buffer
    __shared__ __align__(16) float sh2[64];   // h2 broadcast buffer
    __shared__ float dts[kT];

    for (int i = lane; i < kT - 1; i += 64) dts[i] = tarr[i + 1] - tarr[i];

    sbuf[lane]      = latent[row * 128 + lane];
    sbuf[64 + lane] = latent[row * 128 + 64 + lane];
    __syncthreads();

    // ---- resident weights, volatile-loaded (R11: proven resident) ----
    const volatile float* wsv = ws;
    const volatile float* w2v = W2;

    float2v w2p[16];
    #pragma unroll
    for (int j = 0; j < 16; ++j)
        w2p[j] = float2v{kScale * w2v[(2 * j) * 64 + lane],
                         kScale * w2v[(2 * j + 1) * 64 + lane]};
    float2v w3p[32];
    #pragma unroll
    for (int j = 0; j < 32; ++j)
        w3p[j] = float2v{wsv[kWsM + (2 * j) * 64 + lane],
                         wsv[kWsM + (2 * j + 1) * 64 + lane]};

    const float breg = wsv[kWsMb + lane];
    const float2v mo01 = {wsv[kWsMO + lane * 3 + 0], wsv[kWsMO + lane * 3 + 1]};
    const float mo2 = wsv[kWsMO + lane * 3 + 2];
    const float2v mob01 = (lane == 0)
        ? float2v{wsv[kWsMOb + 0], wsv[kWsMOb + 1]} : float2v{0.f, 0.f};
    const float mobp2 = (lane == 0) ? wsv[kWsMOb + 2] : 0.f;
    const float b2s = kScale * b2[lane];
    const float bo0 = b_obs[0], bo1 = b_obs[1], bo2 = b_obs[2];

    // ---- l1c = scale*(latent @ W1l + b1), replicated to both halves ----
    float l1h = 0.f;
    #pragma unroll 8
    for (int j = 0; j < 64; ++j)
        l1h = fmaf(sbuf[kh * 64 + j], W1[(128 + kh * 64 + j) * 32 + c], l1h);
    const float l1c = kScale * (xsum(l1h) + b1[c]);

    // ---- y0 = latent @ W_l2d + b_l2d ----
    float p0v = b_l2d[lane], v0v = b_l2d[64 + lane];
    #pragma unroll 4
    for (int k = 0; k < 128; ++k) {
        const float lv = sbuf[k];
        p0v = fmaf(lv, W_l2d[k * 128 + lane], p0v);
        v0v = fmaf(lv, W_l2d[k * 128 + 64 + lane], v0v);
    }

    // ---- obs partials (per-lane; reduced only at emit) ----
    const float woa = W_obs[lane * 3 + 0], wob = W_obs[lane * 3 + 1], woc = W_obs[lane * 3 + 2];
    float op0 = p0v * woa, op1 = p0v * wob, op2 = p0v * woc;
    float ov0 = v0v * woa, ov1 = v0v * wob, ov2 = v0v * woc;

    // ---- project state: x = scale*(pos0@W1p | vel0@W1v), V1 = scale*vel0@W1p ----
    __syncthreads();
    sbuf[lane]      = p0v;
    sbuf[64 + lane] = v0v;
    __syncthreads();
    float xacc = 0.f, vacc = 0.f;
    #pragma unroll 4
    for (int j = 0; j < 64; ++j) {
        xacc = fmaf(sbuf[kh * 64 + j], W1[(kh * 64 + j) * 32 + c], xacc);
        vacc = fmaf(sbuf[64 + j],      W1[j * 32 + c],             vacc);
    }
    float x  = kScale * xacc;
    float V1 = kScale * vacc;

    const float4* __restrict__ sh1_4 = reinterpret_cast<const float4*>(sh1);
    const float4* __restrict__ sh2_4 = reinterpret_cast<const float4*>(sh2);

    // dyn: ALL-LDS broadcast (R17 body — HW-validated bit-identical) now that
    // the DS pipe is exclusive to dyn (R18 moved emit to VALU DPP).
    // ds_write -> issue all reads -> independent VALU (q's, RK glue hoisted
    // by the scheduler) -> MACs in read order. Accumulator grouping k-mod-4
    // ascending, (x,y)->accA (z,w)->accB -> bit-identical.
    auto dyn = [&](float xs, float2v& q01, float& q2, float& A) {
        const float pre = xsum(xs) + l1c;
        const float h1 = __builtin_amdgcn_cosf(pre);
        sh1[lane] = h1;                              // ds_write (64 slots)
        float4 rv1[8];
        #pragma unroll
        for (int r = 0; r < 8; ++r) rv1[r] = sh1_4[r];       // k = 0..31
        float2v aA = {b2s, 0.f}, aB = {0.f, 0.f};
        #pragma unroll
        for (int r = 0; r < 8; ++r) {                // k = 0..31 via LDS
            const float2v h01 = {rv1[r].x, rv1[r].y};
            const float2v h23 = {rv1[r].z, rv1[r].w};
            aA = pk_fma(h01, w2p[2 * r + 0], aA);
            aB = pk_fma(h23, w2p[2 * r + 1], aB);
        }
        const float h2 = __builtin_amdgcn_cosf((aA.x + aA.y) + (aB.x + aB.y));
        sh2[lane] = h2;                              // ds_write
        float4 rv2[16];
        #pragma unroll
        for (int r = 0; r < 16; ++r) rv2[r] = sh2_4[r];      // k = 0..63
        q01 = pk_fma(float2v{h2, h2}, mo01, mob01);
        q2  = fmaf(h2, mo2, mobp2);
        float2v cA = {breg, 0.f}, cB = {0.f, 0.f};
        #pragma unroll
        for (int r = 0; r < 16; ++r) {               // k = 0..63 via LDS
            const float2v h01 = {rv2[r].x, rv2[r].y};
            const float2v h23 = {rv2[r].z, rv2[r].w};
            cA = pk_fma(h01, w3p[2 * r + 0], cA);
            cB = pk_fma(h23, w3p[2 * r + 1], cB);
        }
        A = (cA.x + cA.y) + (cB.x + cB.y);
    };

    // emit: all-VALU DPP tree (no DS ops); store from lane 63. (R18, -68 us)
    auto emit = [&](int tt) {
        const float r0 = wave_sum63(op0);
        const float r1 = wave_sum63(op1);
        const float r2 = wave_sum63(op2);
        if (lane == 63) {
            *reinterpret_cast<float2*>(out + ((size_t)tt * kB + row) * 2) =
                make_float2(r0 + bo0, r1 + bo1);
            const float z = r2 + bo2;
            out[kOffP + (size_t)tt * kB + row] = 1.f / (1.f + __expf(-z));
            out[kOffL + (size_t)tt * kB + row] = 0.f;
        }
    };

    const bool lo = (kh == 0);
    for (int tt = 0; tt < kT - 1; ++tt) {
        // dyn1 first; emit's VALU tree interleaves with dyn1's DS waits.
        float A1, u12; float2v u101; dyn(x, u101, u12, A1);
        const float dt = dts[tt];
        emit(tt);
        const float cc = dt * (1.f / 3.f);
        const float u10 = u101.x, u11 = u101.y;

        const float k1  = lo ? V1 : A1;
        const float x2  = fmaf(cc, k1, x);
        const float V1b = fmaf(cc, A1, V1);
        const float w10 = fmaf(cc, u10, ov0);
        const float w11 = fmaf(cc, u11, ov1);
        const float w12 = fmaf(cc, u12, ov2);

        float A2, u22; float2v u201; dyn(x2, u201, u22, A2);
        const float u20 = u201.x, u21 = u201.y;
        const float k2  = lo ? V1b : A2;
        const float x3  = fmaf(dt, fmaf(-1.f / 3.f, k1, k2), x);
        const float V1c = fmaf(dt, fmaf(-1.f / 3.f, A1, A2), V1);
        const float w20 = fmaf(dt, fmaf(-1.f / 3.f, u10, u20), ov0);
        const float w21 = fmaf(dt, fmaf(-1.f / 3.f, u11, u21), ov1);
        const float w22 = fmaf(dt, fmaf(-1.f / 3.f, u12, u22), ov2);

        float A3, u32; float2v u301; dyn(x3, u301, u32, A3);
        const float u30 = u301.x, u31 = u301.y;
        const float k3  = lo ? V1c : A3;
        const float x4  = fmaf(dt, k1 - k2 + k3, x);
        const float V1d = fmaf(dt, A1 - A2 + A3, V1);
        const float w30 = fmaf(dt, u10 - u20 + u30, ov0);
        const float w31 = fmaf(dt, u11 - u21 + u31, ov1);
        const float w32 = fmaf(dt, u12 - u22 + u32, ov2);

        float A4, u42; float2v u401; dyn(x4, u401, u42, A4);
        const float u40 = u401.x, u41 = u401.y;
        const float k4 = lo ? V1d : A4;

        const float s = dt * 0.125f;
        x   = fmaf(s, k1 + 3.f * (k2 + k3) + k4, x);
        V1  = fmaf(s, A1 + 3.f * (A2 + A3) + A4, V1);
        op0 = fmaf(s, ov0 + 3.f * (w10 + w20) + w30, op0);
        op1 = fmaf(s, ov1 + 3.f * (w11 + w21) + w31, op1);
        op2 = fmaf(s, ov2 + 3.f * (w12 + w22) + w32, op2);
        ov0 = fmaf(s, u10 + 3.f * (u20 + u30) + u40, ov0);
        ov1 = fmaf(s, u11 + 3.f * (u21 + u31) + u41, ov1);
        ov2 = fmaf(s, u12 + 3.f * (u22 + u32) + u42, ov2);
    }
    emit(kT - 1);
}

extern "C" void kernel_launch(void* const* d_in, const int* in_sizes, int n_in,
                              void* d_out, int out_size, void* d_ws, size_t ws_size,
                              hipStream_t stream) {
    (void)in_sizes; (void)n_in; (void)ws_size; (void)out_size;
    const float* latent = (const float*)d_in[0];
    const float* tarr   = (const float*)d_in[1];
    const float* W_l2d  = (const float*)d_in[2];
    const float* b_l2d  = (const float*)d_in[3];
    const float* W1     = (const float*)d_in[4];
    const float* b1     = (const float*)d_in[5];
    const float* W2     = (const float*)d_in[6];
    const float* b2     = (const float*)d_in[7];
    const float* W3     = (const float*)d_in[8];
    const float* b3     = (const float*)d_in[9];
    const float* W_obs  = (const float*)d_in[10];
    const float* b_obs  = (const float*)d_in[11];
    float* ws = (float*)d_ws;

    setup_kernel<<<dim3(18), dim3(256), 0, stream>>>(W1, W3, W_obs, b3, ws);
    ode_seq_kernel<<<dim3(kB), dim3(64), 0, stream>>>(
        latent, tarr, W_l2d, b_l2d, W1, b1, W2, b2, W_obs, b_obs, ws,
        (float*)d_out);
}